// Round 9
// baseline (206.903 us; speedup 1.0000x reference)
//
#include <hip/hip_runtime.h>
#include <math.h>

#define LOOKBACK 336
#define NFEAT    164
#define HORIZON  96
#define DMODEL   64
#define DSTATE   16
#define DINNER   128
#define MLPH     64
#define BATCH    512
#define XCP      132
#define NG       4      // channel-groups (time segments) per block
#define GSEG     84     // timesteps per group
#define CHK      12     // timesteps per chunk
#define NCH      7      // chunks per group (7*12 = 84)
#define HSTR     20     // hpart record stride (breaks stride-16 bank aliasing)

typedef float v2f __attribute__((ext_vector_type(2)));

__device__ __forceinline__ float fast_rcp(float x) { return __builtin_amdgcn_rcpf(x); }
__device__ __forceinline__ float silu_f(float x) {
    return x * fast_rcp(1.f + __expf(-x));
}

// R9 = R8 (wave-specialized phases: [pair-A2(c) || conv(c+1)] | bar | scan | bar)
// + explicit 2-stage software pipeline in the scan: tt+1's dtraw/Bsh/xs loads
// are issued (named rotation registers) before tt's compute, hiding the
// ~120-cycle LDS latency under the ~76-cycle per-tt VALU/trans work.
// VGPR headroom: (512,2) allows 128 VGPR at unchanged 16 waves/CU (grid-capped).
__global__ __launch_bounds__(512, 2) void mamba_one(
    const float* __restrict__ x_raw,   const float* __restrict__ x_features,
    const float* __restrict__ embed_W, const float* __restrict__ embed_b,
    const float* __restrict__ in_W,
    const float* __restrict__ conv_W,  const float* __restrict__ conv_b,
    const float* __restrict__ xproj_W, const float* __restrict__ dt_W,
    const float* __restrict__ dt_b,    const float* __restrict__ A_log,
    const float* __restrict__ Dvec,    const float* __restrict__ out_W,
    const float* __restrict__ mlp_W1,  const float* __restrict__ mlp_b1,
    const float* __restrict__ mlp_W2,  const float* __restrict__ mlp_b2,
    const float* __restrict__ head_W,  const float* __restrict__ head_b,
    float* __restrict__ out)
{
    __shared__ __align__(16) float xrl[344];            // xrl[i]=x_raw[i-3], pad i<3
    __shared__ __align__(16) float xprojT[20*XCP];      // 10.6 KB
    __shared__ __align__(16) float xcbuf[2][NG][CHK*XCP]; // 50.7 KB double-buffered
    __shared__ __align__(16) float Bsh[NG][CHK][DSTATE];
    __shared__ __align__(16) float dtraw[NG][CHK][4];
    __shared__ float xcl[DINNER], zsil[DINNER], Cl[DSTATE], yv[DINNER];
    __shared__ float hfin[96], mlph[MLPH];

    const int tid = threadIdx.x;
    const int b   = blockIdx.x;
    const int g   = tid >> 7;            // group 0..3 (2 waves, wave-uniform)
    const int ch  = tid & 127;

    // ---- staging ----
    for (int i = tid; i < 339; i += 512)
        xrl[i] = (i >= 3) ? x_raw[b*LOOKBACK + i - 3] : 0.f;
    for (int idx = tid; idx < 20*DINNER; idx += 512) {
        int jj = idx >> 7, d = idx & 127;
        xprojT[jj*XCP + d] = xproj_W[d*36 + jj];
    }

    // ---- per-thread channel params (embed_* uniform -> scalar loads) ----
    float w1 = 0.f, w0 = 0.f;
    for (int dm = 0; dm < DMODEL; ++dm) {
        float w = in_W[dm*(2*DINNER) + ch];
        w1 = fmaf(embed_W[dm], w, w1);
        w0 = fmaf(embed_b[dm], w, w0);
    }
    const float4 cw = *(const float4*)&conv_W[ch*4];
    const float  cb = conv_b[ch];
    const float dtw0 = dt_W[ch],       dtw1 = dt_W[128 + ch],
                dtw2 = dt_W[256 + ch], dtw3 = dt_W[384 + ch];
    const float dtb_r = dt_b[ch];
    bool structured = true;
    #pragma unroll
    for (int i = 0; i < 16; ++i) {
        float a = __expf(A_log[ch*DSTATE + i]);
        float ex = (float)(i + 1);
        structured = structured && (fabsf(a - ex) < 1e-3f * ex);
    }
    const bool sfast = __all(structured);

    // pair-A2 task decode (waves 0-3, tid<240): lane covers groups 2*sub,+1
    const int a2jp  = tid / 24;              // 0..9 for tid<240
    const int a2rem = tid - a2jp*24;
    const int a2sub = a2rem / 12;            // 0 or 1
    const int a2tt  = a2rem - a2sub*12;      // 0..11
    // dual-conv decode (waves 4-7): channel + first group of {g, g+2}
    const int cch    = (tid - 256) & 127;
    const int gfirst = (tid - 256) >> 7;     // 0 (waves 4,5) or 1 (waves 6,7)
    __syncthreads();   // xrl/xprojT ready

    // ---- conv chunk 0 into buffer 0 (all threads, own (g,ch)) ----
    {
        float* xw = &xcbuf[0][g][0];
        const float* xr = &xrl[g*GSEG];
        if (g == 0) {        // zero-padded taps at sequence start
            for (int tt = 0; tt < CHK; ++tt) {
                float acc = cb;
                if (tt >= 3) acc = fmaf(fmaf(xr[tt],   w1, w0), cw.x, acc);
                if (tt >= 2) acc = fmaf(fmaf(xr[tt+1], w1, w0), cw.y, acc);
                if (tt >= 1) acc = fmaf(fmaf(xr[tt+2], w1, w0), cw.z, acc);
                acc = fmaf(fmaf(xr[tt+3], w1, w0), cw.w, acc);
                xw[tt*XCP + ch] = silu_f(acc);
            }
        } else {
            float e0 = fmaf(xr[0], w1, w0);
            float e1 = fmaf(xr[1], w1, w0);
            float e2 = fmaf(xr[2], w1, w0);
            #pragma unroll
            for (int tt = 0; tt < CHK; ++tt) {
                float e3 = fmaf(xr[tt+3], w1, w0);
                float acc = cb + e0*cw.x + e1*cw.y + e2*cw.z + e3*cw.w;
                xw[tt*XCP + ch] = silu_f(acc);
                e0 = e1; e1 = e2; e2 = e3;
            }
        }
    }
    __syncthreads();

    // ---- main loop: [A2(c) || conv(c+1)] | bar | scan(c) | bar ----
    v2f h01={0,0},h23={0,0},h45={0,0},h67={0,0},
        h89={0,0},hAB={0,0},hCD={0,0},hEF={0,0};
    float dacc = 0.f;

    for (int c = 0; c < NCH; ++c) {
        const int buf = c & 1;

        if (tid < 240) {
            // pair-A2: 1 xproj column pair (broadcast in 24-lane span),
            // 2 xrows (one per group of its pair). Reads buf.
            const int ga = a2sub*2, gb = a2sub*2 + 1;
            const int j0 = a2jp*2;
            const float* p0  = &xprojT[j0*XCP];
            const float* p1  = &xprojT[(j0+1)*XCP];
            const float* xra = &xcbuf[buf][ga][a2tt*XCP];
            const float* xrb = &xcbuf[buf][gb][a2tt*XCP];
            v2f a0a={0,0}, a1a={0,0}, a0b={0,0}, a1b={0,0};
            #pragma unroll 4
            for (int d = 0; d < DINNER; d += 4) {
                float4 q0 = *(const float4*)(p0 + d);
                float4 q1 = *(const float4*)(p1 + d);
                float4 xa = *(const float4*)(xra + d);
                float4 xb = *(const float4*)(xrb + d);
                v2f q0l={q0.x,q0.y}, q0h={q0.z,q0.w};
                v2f q1l={q1.x,q1.y}, q1h={q1.z,q1.w};
                v2f xal={xa.x,xa.y}, xah={xa.z,xa.w};
                v2f xbl={xb.x,xb.y}, xbh={xb.z,xb.w};
                a0a = __builtin_elementwise_fma(xal, q0l, a0a);
                a0a = __builtin_elementwise_fma(xah, q0h, a0a);
                a1a = __builtin_elementwise_fma(xal, q1l, a1a);
                a1a = __builtin_elementwise_fma(xah, q1h, a1a);
                a0b = __builtin_elementwise_fma(xbl, q0l, a0b);
                a0b = __builtin_elementwise_fma(xbh, q0h, a0b);
                a1b = __builtin_elementwise_fma(xbl, q1l, a1b);
                a1b = __builtin_elementwise_fma(xbh, q1h, a1b);
            }
            float r0a=a0a.x+a0a.y, r1a=a1a.x+a1a.y;
            float r0b=a0b.x+a0b.y, r1b=a1b.x+a1b.y;
            if (j0 < 4) {
                *(float2*)&dtraw[ga][a2tt][j0] = make_float2(r0a, r1a);
                *(float2*)&dtraw[gb][a2tt][j0] = make_float2(r0b, r1b);
            } else {
                *(float2*)&Bsh[ga][a2tt][j0-4] = make_float2(r0a, r1a);
                *(float2*)&Bsh[gb][a2tt][j0-4] = make_float2(r0b, r1b);
            }
        } else if (tid >= 256 && c + 1 < NCH) {
            // dual-conv: chunk c+1 for groups gfirst and gfirst+2 into buf^1.
            // t0 = gg*84 + (c+1)*12 >= 12, so no zero-pad branch needed.
            #pragma unroll
            for (int q = 0; q < 2; ++q) {
                const int gg = gfirst + q*2;
                float* xw = &xcbuf[buf^1][gg][0];
                const float* xr = &xrl[gg*GSEG + (c+1)*CHK];
                float e0 = fmaf(xr[0], w1, w0);
                float e1 = fmaf(xr[1], w1, w0);
                float e2 = fmaf(xr[2], w1, w0);
                float v = 0.f;
                #pragma unroll
                for (int tt = 0; tt < CHK; ++tt) {
                    float e3 = fmaf(xr[tt+3], w1, w0);
                    float acc = cb + e0*cw.x + e1*cw.y + e2*cw.z + e3*cw.w;
                    v = silu_f(acc);
                    xw[tt*XCP + cch] = v;
                    e0 = e1; e1 = e2; e2 = e3;
                }
                if (gg == NG-1 && c + 1 == NCH-1) xcl[cch] = v;   // t = 335
            }
        }
        __syncthreads();   // dtraw/Bsh(c) + conv(c+1) ready

        // ---- phase 2: pure scan chunk c (reads buf), 2-stage pipelined ----
        const float* xs = &xcbuf[buf][g][0];
        if (__builtin_expect(sfast, 1)) {
            // preload tt = 0
            float4 drA = *(const float4*)&dtraw[g][0][0];
            float4 B0A = *(const float4*)&Bsh[g][0][0];
            float4 B1A = *(const float4*)&Bsh[g][0][4];
            float4 B2A = *(const float4*)&Bsh[g][0][8];
            float4 B3A = *(const float4*)&Bsh[g][0][12];
            float  xvA = xs[ch];
            #pragma unroll
            for (int tt = 0; tt < CHK; ++tt) {
                float4 dr = drA;
                float4 B0 = B0A, B1 = B1A, B2 = B2A, B3 = B3A;
                float  xv = xvA;
                if (tt + 1 < CHK) {                      // prefetch tt+1
                    drA = *(const float4*)&dtraw[g][tt+1][0];
                    B0A = *(const float4*)&Bsh[g][tt+1][0];
                    B1A = *(const float4*)&Bsh[g][tt+1][4];
                    B2A = *(const float4*)&Bsh[g][tt+1][8];
                    B3A = *(const float4*)&Bsh[g][tt+1][12];
                    xvA = xs[(tt+1)*XCP + ch];
                }
                float dv = fmaf(dr.x, dtw0, fmaf(dr.y, dtw1,
                           fmaf(dr.z, dtw2, fmaf(dr.w, dtw3, dtb_r))));
                float e  = __expf(dv);
                float p  = 1.f + e;
                float r  = fast_rcp(p);                  // exp(-delta)
                float dl = (dv > 80.f) ? dv : __logf(p); // delta
                dacc += dl;
                float ux = dl * xv;
                // shallow power tree: depth 3 instead of 8
                float r2 = r*r, r4 = r2*r2, r8 = r4*r4;
                v2f r2v = {r2, r2}, r4v = {r4, r4}, r8v = {r8, r8};
                v2f p01 = {r, r2};
                v2f p23 = p01*r2v;
                v2f p45 = p01*r4v, p67 = p23*r4v;
                v2f p89 = p01*r8v, pAB = p23*r8v, pCD = p45*r8v, pEF = p67*r8v;
                v2f uxv = {ux, ux};
                h01 = __builtin_elementwise_fma(p01, h01, uxv*(v2f){B0.x,B0.y});
                h23 = __builtin_elementwise_fma(p23, h23, uxv*(v2f){B0.z,B0.w});
                h45 = __builtin_elementwise_fma(p45, h45, uxv*(v2f){B1.x,B1.y});
                h67 = __builtin_elementwise_fma(p67, h67, uxv*(v2f){B1.z,B1.w});
                h89 = __builtin_elementwise_fma(p89, h89, uxv*(v2f){B2.x,B2.y});
                hAB = __builtin_elementwise_fma(pAB, hAB, uxv*(v2f){B2.z,B2.w});
                hCD = __builtin_elementwise_fma(pCD, hCD, uxv*(v2f){B3.x,B3.y});
                hEF = __builtin_elementwise_fma(pEF, hEF, uxv*(v2f){B3.z,B3.w});
            }
        } else {
            const float* Arow = A_log + ch*DSTATE;
            for (int tt = 0; tt < CHK; ++tt) {
                float4 dr = *(const float4*)&dtraw[g][tt][0];
                float dv = fmaf(dr.x, dtw0, fmaf(dr.y, dtw1,
                           fmaf(dr.z, dtw2, fmaf(dr.w, dtw3, dtb_r))));
                float e  = __expf(dv);
                float dl = (dv > 15.f) ? dv : __logf(1.f + e);
                dacc += dl;
                float ux = dl * xs[tt*XCP + ch];
                const float* Brow = &Bsh[g][tt][0];
                float hv[16] = {h01.x,h01.y,h23.x,h23.y,h45.x,h45.y,h67.x,h67.y,
                                h89.x,h89.y,hAB.x,hAB.y,hCD.x,hCD.y,hEF.x,hEF.y};
                for (int i = 0; i < 16; ++i)
                    hv[i] = fmaf(__expf(-__expf(Arow[i])*dl), hv[i], ux*Brow[i]);
                h01=(v2f){hv[0],hv[1]};   h23=(v2f){hv[2],hv[3]};
                h45=(v2f){hv[4],hv[5]};   h67=(v2f){hv[6],hv[7]};
                h89=(v2f){hv[8],hv[9]};   hAB=(v2f){hv[10],hv[11]};
                hCD=(v2f){hv[12],hv[13]}; hEF=(v2f){hv[14],hv[15]};
            }
        }
        __syncthreads();   // scan reads done before next A2/conv overwrite
    }

    // ---- write partials to LDS (overlay dead xcbuf / Bsh regions) ----
    float* hpart = &xcbuf[0][0][0];      // needs 512*HSTR = 10240 <= 12672
    float* dsum  = &Bsh[0][0][0];        // needs 512 <= 768
    {
        float4* hp = (float4*)&hpart[(g*128 + ch)*HSTR];
        hp[0] = make_float4(h01.x,h01.y,h23.x,h23.y);
        hp[1] = make_float4(h45.x,h45.y,h67.x,h67.y);
        hp[2] = make_float4(h89.x,h89.y,hAB.x,hAB.y);
        hp[3] = make_float4(hCD.x,hCD.y,hEF.x,hEF.y);
        dsum[g*128 + ch] = dacc;
    }
    __syncthreads();

    // ---- E1 (parallel): combine | z-gate | C | mlp1 ----
    float H[16];
    if (tid < 128) {
        {
            const float4* hp = (const float4*)&hpart[tid*HSTR];
            float4 a = hp[0], bq = hp[1], cq = hp[2], dq = hp[3];
            H[0]=a.x;  H[1]=a.y;  H[2]=a.z;  H[3]=a.w;
            H[4]=bq.x; H[5]=bq.y; H[6]=bq.z; H[7]=bq.w;
            H[8]=cq.x; H[9]=cq.y; H[10]=cq.z;H[11]=cq.w;
            H[12]=dq.x;H[13]=dq.y;H[14]=dq.z;H[15]=dq.w;
        }
        for (int gg = 1; gg < NG; ++gg) {
            float D = dsum[gg*128 + tid];
            const float4* hp = (const float4*)&hpart[(gg*128 + tid)*HSTR];
            float4 a = hp[0], bq = hp[1], cq = hp[2], dq = hp[3];
            float hg[16] = {a.x,a.y,a.z,a.w,bq.x,bq.y,bq.z,bq.w,
                            cq.x,cq.y,cq.z,cq.w,dq.x,dq.y,dq.z,dq.w};
            if (structured) {
                float r = __expf(-D);
                float pw = 1.f;
                #pragma unroll
                for (int i = 0; i < 16; ++i) {
                    pw *= r;                      // r^(i+1)
                    H[i] = fmaf(pw, H[i], hg[i]);
                }
            } else {
                #pragma unroll
                for (int i = 0; i < 16; ++i)
                    H[i] = fmaf(__expf(-__expf(A_log[tid*DSTATE+i])*D), H[i], hg[i]);
            }
        }
    } else if (tid < 256) {
        const int c2 = tid - 128;                 // z-gate channel
        float a1 = 0.f, a0 = 0.f;
        for (int dm = 0; dm < DMODEL; ++dm) {
            float w = in_W[dm*(2*DINNER) + DINNER + c2];
            a1 = fmaf(embed_W[dm], w, a1);
            a0 = fmaf(embed_b[dm], w, a0);
        }
        float zv = fmaf(xrl[338], a1, a0);        // x_raw[335]
        zsil[c2] = silu_f(zv);
    } else if (tid < 320) {
        const int lane = tid - 256;               // C at t=335 (one wave)
        const int n = lane & 15, q = lane >> 4;
        float acc = 0.f;
        for (int d = q*32; d < q*32 + 32; ++d)
            acc = fmaf(xcl[d], xproj_W[d*36 + 20 + n], acc);
        acc += __shfl_xor(acc, 16);
        acc += __shfl_xor(acc, 32);
        if (lane < 16) Cl[n] = acc;
    } else if (tid >= 384) {
        const int lane = tid - 384;               // mlp1 (2 waves)
        const int j = lane >> 1, k = lane & 1;
        const float* xf = x_features + b*NFEAT;
        float acc = 0.f;
        const int f0 = k*82, f1 = (k ? NFEAT : 82);
        for (int f = f0; f < f1; ++f)
            acc = fmaf(xf[f], mlp_W1[f*MLPH + j], acc);
        acc += __shfl_xor(acc, 1);
        if (k == 0) mlph[j] = fmaxf(acc + mlp_b1[j], 0.f);
    }
    __syncthreads();

    // ---- E2: y (tid<128) | mlp2 (tid 128..191) ----
    if (tid < 128) {
        float acc = 0.f;
        #pragma unroll
        for (int i = 0; i < 16; ++i) acc = fmaf(H[i], Cl[i], acc);
        float y = acc + xcl[tid]*Dvec[tid];
        yv[tid] = y * zsil[tid];
    } else if (tid < 192) {
        const int lane = tid - 128;
        const int j = lane >> 1, k = lane & 1;
        float acc = 0.f;
        for (int kk = k*32; kk < k*32 + 32; ++kk)
            acc = fmaf(mlph[kk], mlp_W2[kk*32 + j], acc);
        acc += __shfl_xor(acc, 1);
        if (k == 0) hfin[64 + j] = acc + mlp_b2[j];
    }
    __syncthreads();

    // ---- E3: out projection (tid<256) ----
    if (tid < 256) {
        const int o = tid >> 2, k = tid & 3;
        float acc = 0.f;
        for (int d = k*32; d < k*32 + 32; ++d)
            acc = fmaf(yv[d], out_W[d*DMODEL + o], acc);
        acc += __shfl_xor(acc, 1);
        acc += __shfl_xor(acc, 2);
        if (k == 0) hfin[o] = acc;
    }
    __syncthreads();

    // ---- E4: head ----
    if (tid < 192) {
        const int o = tid >> 1, k = tid & 1;
        float acc = 0.f;
        for (int i = k*48; i < k*48 + 48; ++i)
            acc = fmaf(hfin[i], head_W[i*HORIZON + o], acc);
        acc += __shfl_xor(acc, 1);
        if (k == 0) out[b*HORIZON + o] = acc + head_b[o];
    }
}

extern "C" void kernel_launch(void* const* d_in, const int* in_sizes, int n_in,
                              void* d_out, int out_size, void* d_ws, size_t ws_size,
                              hipStream_t stream) {
    (void)in_sizes; (void)n_in; (void)out_size; (void)d_ws; (void)ws_size;
    mamba_one<<<BATCH, 512, 0, stream>>>(
        (const float*)d_in[0],  (const float*)d_in[1],  (const float*)d_in[2],
        (const float*)d_in[3],  (const float*)d_in[4],  (const float*)d_in[5],
        (const float*)d_in[6],  (const float*)d_in[7],  (const float*)d_in[8],
        (const float*)d_in[9],  (const float*)d_in[10], (const float*)d_in[11],
        (const float*)d_in[12], (const float*)d_in[13], (const float*)d_in[14],
        (const float*)d_in[15], (const float*)d_in[16], (const float*)d_in[17],
        (const float*)d_in[18], (float*)d_out);
}

// Round 10
// 191.536 us; speedup vs baseline: 1.0802x; 1.0802x over previous
//
#include <hip/hip_runtime.h>
#include <math.h>

#define LOOKBACK 336
#define NFEAT    164
#define HORIZON  96
#define DMODEL   64
#define DSTATE   16
#define DINNER   128
#define MLPH     64
#define BATCH    512
#define XCP      132
#define NG       4      // channel-groups (time segments) per block
#define GSEG     84     // timesteps per group
#define CHK      12     // timesteps per chunk
#define NCH      7      // chunks per group (7*12 = 84)
#define HSTR     20     // hpart record stride (breaks stride-16 bank aliasing)

typedef float v2f __attribute__((ext_vector_type(2)));

__device__ __forceinline__ float fast_rcp(float x) { return __builtin_amdgcn_rcpf(x); }
__device__ __forceinline__ float silu_f(float x) {
    return x * fast_rcp(1.f + __expf(-x));
}

// R10 = R8 (best: wave-specialized [pair-A2(c) || conv(c+1)] | bar | scan | bar)
// + (a) launch_bounds(512,4): 2nd arg = min waves/EU -> hard 64-VGPR cap.
//   VGPR>64 drops to 3 waves/SIMD -> only ONE 512-thread block/CU (observed
//   22.5% occupancy in R1/R4/R9). R8 fits in 64; pin it.
// + (b) last-chunk slack reclaim: in iter c=NCH-1 phase 1, waves 4-7 have no
//   conv to do -- run the one-shot z-gate / C / mlp1 side tasks there, so the
//   E1 epilogue is combine-only.
__global__ __launch_bounds__(512, 4) void mamba_one(
    const float* __restrict__ x_raw,   const float* __restrict__ x_features,
    const float* __restrict__ embed_W, const float* __restrict__ embed_b,
    const float* __restrict__ in_W,
    const float* __restrict__ conv_W,  const float* __restrict__ conv_b,
    const float* __restrict__ xproj_W, const float* __restrict__ dt_W,
    const float* __restrict__ dt_b,    const float* __restrict__ A_log,
    const float* __restrict__ Dvec,    const float* __restrict__ out_W,
    const float* __restrict__ mlp_W1,  const float* __restrict__ mlp_b1,
    const float* __restrict__ mlp_W2,  const float* __restrict__ mlp_b2,
    const float* __restrict__ head_W,  const float* __restrict__ head_b,
    float* __restrict__ out)
{
    __shared__ __align__(16) float xrl[344];            // xrl[i]=x_raw[i-3], pad i<3
    __shared__ __align__(16) float xprojT[20*XCP];      // 10.6 KB
    __shared__ __align__(16) float xcbuf[2][NG][CHK*XCP]; // 50.7 KB double-buffered
    __shared__ __align__(16) float Bsh[NG][CHK][DSTATE];
    __shared__ __align__(16) float dtraw[NG][CHK][4];
    __shared__ float xcl[DINNER], zsil[DINNER], Cl[DSTATE], yv[DINNER];
    __shared__ float hfin[96], mlph[MLPH];

    const int tid = threadIdx.x;
    const int b   = blockIdx.x;
    const int g   = tid >> 7;            // group 0..3 (2 waves, wave-uniform)
    const int ch  = tid & 127;

    // ---- staging ----
    for (int i = tid; i < 339; i += 512)
        xrl[i] = (i >= 3) ? x_raw[b*LOOKBACK + i - 3] : 0.f;
    for (int idx = tid; idx < 20*DINNER; idx += 512) {
        int jj = idx >> 7, d = idx & 127;
        xprojT[jj*XCP + d] = xproj_W[d*36 + jj];
    }

    // ---- per-thread channel params (embed_* uniform -> scalar loads) ----
    float w1 = 0.f, w0 = 0.f;
    for (int dm = 0; dm < DMODEL; ++dm) {
        float w = in_W[dm*(2*DINNER) + ch];
        w1 = fmaf(embed_W[dm], w, w1);
        w0 = fmaf(embed_b[dm], w, w0);
    }
    const float4 cw = *(const float4*)&conv_W[ch*4];
    const float  cb = conv_b[ch];
    const float dtw0 = dt_W[ch],       dtw1 = dt_W[128 + ch],
                dtw2 = dt_W[256 + ch], dtw3 = dt_W[384 + ch];
    const float dtb_r = dt_b[ch];
    bool structured = true;
    #pragma unroll
    for (int i = 0; i < 16; ++i) {
        float a = __expf(A_log[ch*DSTATE + i]);
        float ex = (float)(i + 1);
        structured = structured && (fabsf(a - ex) < 1e-3f * ex);
    }
    const bool sfast = __all(structured);

    // pair-A2 task decode (waves 0-3, tid<240): lane covers groups 2*sub,+1
    const int a2jp  = tid / 24;              // 0..9 for tid<240
    const int a2rem = tid - a2jp*24;
    const int a2sub = a2rem / 12;            // 0 or 1
    const int a2tt  = a2rem - a2sub*12;      // 0..11
    // dual-conv decode (waves 4-7): channel + first group of {g, g+2}
    const int cch    = (tid - 256) & 127;
    const int gfirst = (tid - 256) >> 7;     // 0 (waves 4,5) or 1 (waves 6,7)
    __syncthreads();   // xrl/xprojT ready

    // ---- conv chunk 0 into buffer 0 (all threads, own (g,ch)) ----
    {
        float* xw = &xcbuf[0][g][0];
        const float* xr = &xrl[g*GSEG];
        if (g == 0) {        // zero-padded taps at sequence start
            for (int tt = 0; tt < CHK; ++tt) {
                float acc = cb;
                if (tt >= 3) acc = fmaf(fmaf(xr[tt],   w1, w0), cw.x, acc);
                if (tt >= 2) acc = fmaf(fmaf(xr[tt+1], w1, w0), cw.y, acc);
                if (tt >= 1) acc = fmaf(fmaf(xr[tt+2], w1, w0), cw.z, acc);
                acc = fmaf(fmaf(xr[tt+3], w1, w0), cw.w, acc);
                xw[tt*XCP + ch] = silu_f(acc);
            }
        } else {
            float e0 = fmaf(xr[0], w1, w0);
            float e1 = fmaf(xr[1], w1, w0);
            float e2 = fmaf(xr[2], w1, w0);
            #pragma unroll
            for (int tt = 0; tt < CHK; ++tt) {
                float e3 = fmaf(xr[tt+3], w1, w0);
                float acc = cb + e0*cw.x + e1*cw.y + e2*cw.z + e3*cw.w;
                xw[tt*XCP + ch] = silu_f(acc);
                e0 = e1; e1 = e2; e2 = e3;
            }
        }
    }
    __syncthreads();

    // ---- main loop: [A2(c) || conv(c+1) / side-tasks] | bar | scan(c) | bar
    v2f h01={0,0},h23={0,0},h45={0,0},h67={0,0},
        h89={0,0},hAB={0,0},hCD={0,0},hEF={0,0};
    float dacc = 0.f;

    for (int c = 0; c < NCH; ++c) {
        const int buf = c & 1;

        if (tid < 240) {
            // pair-A2: 1 xproj column pair (broadcast in 24-lane span),
            // 2 xrows (one per group of its pair). Reads buf.
            const int ga = a2sub*2, gb = a2sub*2 + 1;
            const int j0 = a2jp*2;
            const float* p0  = &xprojT[j0*XCP];
            const float* p1  = &xprojT[(j0+1)*XCP];
            const float* xra = &xcbuf[buf][ga][a2tt*XCP];
            const float* xrb = &xcbuf[buf][gb][a2tt*XCP];
            v2f a0a={0,0}, a1a={0,0}, a0b={0,0}, a1b={0,0};
            #pragma unroll 4
            for (int d = 0; d < DINNER; d += 4) {
                float4 q0 = *(const float4*)(p0 + d);
                float4 q1 = *(const float4*)(p1 + d);
                float4 xa = *(const float4*)(xra + d);
                float4 xb = *(const float4*)(xrb + d);
                v2f q0l={q0.x,q0.y}, q0h={q0.z,q0.w};
                v2f q1l={q1.x,q1.y}, q1h={q1.z,q1.w};
                v2f xal={xa.x,xa.y}, xah={xa.z,xa.w};
                v2f xbl={xb.x,xb.y}, xbh={xb.z,xb.w};
                a0a = __builtin_elementwise_fma(xal, q0l, a0a);
                a0a = __builtin_elementwise_fma(xah, q0h, a0a);
                a1a = __builtin_elementwise_fma(xal, q1l, a1a);
                a1a = __builtin_elementwise_fma(xah, q1h, a1a);
                a0b = __builtin_elementwise_fma(xbl, q0l, a0b);
                a0b = __builtin_elementwise_fma(xbh, q0h, a0b);
                a1b = __builtin_elementwise_fma(xbl, q1l, a1b);
                a1b = __builtin_elementwise_fma(xbh, q1h, a1b);
            }
            float r0a=a0a.x+a0a.y, r1a=a1a.x+a1a.y;
            float r0b=a0b.x+a0b.y, r1b=a1b.x+a1b.y;
            if (j0 < 4) {
                *(float2*)&dtraw[ga][a2tt][j0] = make_float2(r0a, r1a);
                *(float2*)&dtraw[gb][a2tt][j0] = make_float2(r0b, r1b);
            } else {
                *(float2*)&Bsh[ga][a2tt][j0-4] = make_float2(r0a, r1a);
                *(float2*)&Bsh[gb][a2tt][j0-4] = make_float2(r0b, r1b);
            }
        } else if (tid >= 256) {
            if (c + 1 < NCH) {
                // dual-conv: chunk c+1 for groups gfirst, gfirst+2 into buf^1.
                // t0 = gg*84 + (c+1)*12 >= 12, so no zero-pad branch needed.
                #pragma unroll
                for (int q = 0; q < 2; ++q) {
                    const int gg = gfirst + q*2;
                    float* xw = &xcbuf[buf^1][gg][0];
                    const float* xr = &xrl[gg*GSEG + (c+1)*CHK];
                    float e0 = fmaf(xr[0], w1, w0);
                    float e1 = fmaf(xr[1], w1, w0);
                    float e2 = fmaf(xr[2], w1, w0);
                    float v = 0.f;
                    #pragma unroll
                    for (int tt = 0; tt < CHK; ++tt) {
                        float e3 = fmaf(xr[tt+3], w1, w0);
                        float acc = cb + e0*cw.x + e1*cw.y + e2*cw.z + e3*cw.w;
                        v = silu_f(acc);
                        xw[tt*XCP + cch] = v;
                        e0 = e1; e1 = e2; e2 = e3;
                    }
                    if (gg == NG-1 && c + 1 == NCH-1) xcl[cch] = v;  // t = 335
                }
            } else {
                // last chunk: conv slot is idle -> one-shot side tasks here.
                if (tid < 384) {                     // z-gate, channel tid-256
                    const int c2 = tid - 256;
                    float a1 = 0.f, a0 = 0.f;
                    for (int dm = 0; dm < DMODEL; ++dm) {
                        float w = in_W[dm*(2*DINNER) + DINNER + c2];
                        a1 = fmaf(embed_W[dm], w, a1);
                        a0 = fmaf(embed_b[dm], w, a0);
                    }
                    zsil[c2] = silu_f(fmaf(xrl[338], a1, a0));  // x_raw[335]
                } else if (tid < 448) {              // C at t=335 (one wave)
                    const int lane = tid - 384;
                    const int n = lane & 15, q = lane >> 4;
                    float acc = 0.f;
                    for (int d = q*32; d < q*32 + 32; ++d)
                        acc = fmaf(xcl[d], xproj_W[d*36 + 20 + n], acc);
                    acc += __shfl_xor(acc, 16);
                    acc += __shfl_xor(acc, 32);
                    if (lane < 16) Cl[n] = acc;
                } else {                             // mlp1: 64 lanes, full dot
                    const int j = tid - 448;
                    const float* xf = x_features + b*NFEAT;
                    float acc = 0.f;
                    for (int f = 0; f < NFEAT; ++f)
                        acc = fmaf(xf[f], mlp_W1[f*MLPH + j], acc);
                    mlph[j] = fmaxf(acc + mlp_b1[j], 0.f);
                }
            }
        }
        __syncthreads();   // dtraw/Bsh(c) + conv(c+1)/side-tasks ready

        // ---- phase 2: pure scan chunk c (reads buf) ----
        const float* xs = &xcbuf[buf][g][0];
        if (__builtin_expect(sfast, 1)) {
            #pragma unroll
            for (int tt = 0; tt < CHK; ++tt) {
                float4 dr = *(const float4*)&dtraw[g][tt][0];    // broadcast
                float dv = fmaf(dr.x, dtw0, fmaf(dr.y, dtw1,
                           fmaf(dr.z, dtw2, fmaf(dr.w, dtw3, dtb_r))));
                float e  = __expf(dv);
                float p  = 1.f + e;
                float r  = fast_rcp(p);                  // exp(-delta)
                float dl = (dv > 80.f) ? dv : __logf(p); // delta
                dacc += dl;
                float ux = dl * xs[tt*XCP + ch];
                float4 B0 = *(const float4*)&Bsh[g][tt][0];
                float4 B1 = *(const float4*)&Bsh[g][tt][4];
                float4 B2 = *(const float4*)&Bsh[g][tt][8];
                float4 B3 = *(const float4*)&Bsh[g][tt][12];
                // shallow power tree: depth 3 instead of 8
                float r2 = r*r, r4 = r2*r2, r8 = r4*r4;
                v2f r2v = {r2, r2}, r4v = {r4, r4}, r8v = {r8, r8};
                v2f p01 = {r, r2};
                v2f p23 = p01*r2v;
                v2f p45 = p01*r4v, p67 = p23*r4v;
                v2f p89 = p01*r8v, pAB = p23*r8v, pCD = p45*r8v, pEF = p67*r8v;
                v2f uxv = {ux, ux};
                h01 = __builtin_elementwise_fma(p01, h01, uxv*(v2f){B0.x,B0.y});
                h23 = __builtin_elementwise_fma(p23, h23, uxv*(v2f){B0.z,B0.w});
                h45 = __builtin_elementwise_fma(p45, h45, uxv*(v2f){B1.x,B1.y});
                h67 = __builtin_elementwise_fma(p67, h67, uxv*(v2f){B1.z,B1.w});
                h89 = __builtin_elementwise_fma(p89, h89, uxv*(v2f){B2.x,B2.y});
                hAB = __builtin_elementwise_fma(pAB, hAB, uxv*(v2f){B2.z,B2.w});
                hCD = __builtin_elementwise_fma(pCD, hCD, uxv*(v2f){B3.x,B3.y});
                hEF = __builtin_elementwise_fma(pEF, hEF, uxv*(v2f){B3.z,B3.w});
            }
        } else {
            const float* Arow = A_log + ch*DSTATE;
            for (int tt = 0; tt < CHK; ++tt) {
                float4 dr = *(const float4*)&dtraw[g][tt][0];
                float dv = fmaf(dr.x, dtw0, fmaf(dr.y, dtw1,
                           fmaf(dr.z, dtw2, fmaf(dr.w, dtw3, dtb_r))));
                float e  = __expf(dv);
                float dl = (dv > 15.f) ? dv : __logf(1.f + e);
                dacc += dl;
                float ux = dl * xs[tt*XCP + ch];
                const float* Brow = &Bsh[g][tt][0];
                float hv[16] = {h01.x,h01.y,h23.x,h23.y,h45.x,h45.y,h67.x,h67.y,
                                h89.x,h89.y,hAB.x,hAB.y,hCD.x,hCD.y,hEF.x,hEF.y};
                for (int i = 0; i < 16; ++i)
                    hv[i] = fmaf(__expf(-__expf(Arow[i])*dl), hv[i], ux*Brow[i]);
                h01=(v2f){hv[0],hv[1]};   h23=(v2f){hv[2],hv[3]};
                h45=(v2f){hv[4],hv[5]};   h67=(v2f){hv[6],hv[7]};
                h89=(v2f){hv[8],hv[9]};   hAB=(v2f){hv[10],hv[11]};
                hCD=(v2f){hv[12],hv[13]}; hEF=(v2f){hv[14],hv[15]};
            }
        }
        __syncthreads();   // scan reads done before next A2/conv overwrite
    }

    // ---- write partials to LDS (overlay dead xcbuf / Bsh regions) ----
    float* hpart = &xcbuf[0][0][0];      // needs 512*HSTR = 10240 <= 12672
    float* dsum  = &Bsh[0][0][0];        // needs 512 <= 768
    {
        float4* hp = (float4*)&hpart[(g*128 + ch)*HSTR];
        hp[0] = make_float4(h01.x,h01.y,h23.x,h23.y);
        hp[1] = make_float4(h45.x,h45.y,h67.x,h67.y);
        hp[2] = make_float4(h89.x,h89.y,hAB.x,hAB.y);
        hp[3] = make_float4(hCD.x,hCD.y,hEF.x,hEF.y);
        dsum[g*128 + ch] = dacc;
    }
    __syncthreads();

    // ---- E1: combine only (side tasks were done in last chunk's phase 1) --
    float H[16];
    if (tid < 128) {
        {
            const float4* hp = (const float4*)&hpart[tid*HSTR];
            float4 a = hp[0], bq = hp[1], cq = hp[2], dq = hp[3];
            H[0]=a.x;  H[1]=a.y;  H[2]=a.z;  H[3]=a.w;
            H[4]=bq.x; H[5]=bq.y; H[6]=bq.z; H[7]=bq.w;
            H[8]=cq.x; H[9]=cq.y; H[10]=cq.z;H[11]=cq.w;
            H[12]=dq.x;H[13]=dq.y;H[14]=dq.z;H[15]=dq.w;
        }
        for (int gg = 1; gg < NG; ++gg) {
            float D = dsum[gg*128 + tid];
            const float4* hp = (const float4*)&hpart[(gg*128 + tid)*HSTR];
            float4 a = hp[0], bq = hp[1], cq = hp[2], dq = hp[3];
            float hg[16] = {a.x,a.y,a.z,a.w,bq.x,bq.y,bq.z,bq.w,
                            cq.x,cq.y,cq.z,cq.w,dq.x,dq.y,dq.z,dq.w};
            if (structured) {
                float r = __expf(-D);
                float pw = 1.f;
                #pragma unroll
                for (int i = 0; i < 16; ++i) {
                    pw *= r;                      // r^(i+1)
                    H[i] = fmaf(pw, H[i], hg[i]);
                }
            } else {
                #pragma unroll
                for (int i = 0; i < 16; ++i)
                    H[i] = fmaf(__expf(-__expf(A_log[tid*DSTATE+i])*D), H[i], hg[i]);
            }
        }
    }
    __syncthreads();

    // ---- E2: y (tid<128) | mlp2 (tid 128..191) ----
    if (tid < 128) {
        float acc = 0.f;
        #pragma unroll
        for (int i = 0; i < 16; ++i) acc = fmaf(H[i], Cl[i], acc);
        float y = acc + xcl[tid]*Dvec[tid];
        yv[tid] = y * zsil[tid];
    } else if (tid < 192) {
        const int lane = tid - 128;
        const int j = lane >> 1, k = lane & 1;
        float acc = 0.f;
        for (int kk = k*32; kk < k*32 + 32; ++kk)
            acc = fmaf(mlph[kk], mlp_W2[kk*32 + j], acc);
        acc += __shfl_xor(acc, 1);
        if (k == 0) hfin[64 + j] = acc + mlp_b2[j];
    }
    __syncthreads();

    // ---- E3: out projection (tid<256) ----
    if (tid < 256) {
        const int o = tid >> 2, k = tid & 3;
        float acc = 0.f;
        for (int d = k*32; d < k*32 + 32; ++d)
            acc = fmaf(yv[d], out_W[d*DMODEL + o], acc);
        acc += __shfl_xor(acc, 1);
        acc += __shfl_xor(acc, 2);
        if (k == 0) hfin[o] = acc;
    }
    __syncthreads();

    // ---- E4: head ----
    if (tid < 192) {
        const int o = tid >> 1, k = tid & 1;
        float acc = 0.f;
        for (int i = k*48; i < k*48 + 48; ++i)
            acc = fmaf(hfin[i], head_W[i*HORIZON + o], acc);
        acc += __shfl_xor(acc, 1);
        if (k == 0) out[b*HORIZON + o] = acc + head_b[o];
    }
}

extern "C" void kernel_launch(void* const* d_in, const int* in_sizes, int n_in,
                              void* d_out, int out_size, void* d_ws, size_t ws_size,
                              hipStream_t stream) {
    (void)in_sizes; (void)n_in; (void)out_size; (void)d_ws; (void)ws_size;
    mamba_one<<<BATCH, 512, 0, stream>>>(
        (const float*)d_in[0],  (const float*)d_in[1],  (const float*)d_in[2],
        (const float*)d_in[3],  (const float*)d_in[4],  (const float*)d_in[5],
        (const float*)d_in[6],  (const float*)d_in[7],  (const float*)d_in[8],
        (const float*)d_in[9],  (const float*)d_in[10], (const float*)d_in[11],
        (const float*)d_in[12], (const float*)d_in[13], (const float*)d_in[14],
        (const float*)d_in[15], (const float*)d_in[16], (const float*)d_in[17],
        (const float*)d_in[18], (float*)d_out);
}

// Round 11
// 169.679 us; speedup vs baseline: 1.2194x; 1.1288x over previous
//
#include <hip/hip_runtime.h>
#include <math.h>

#define LOOKBACK 336
#define NFEAT    164
#define HORIZON  96
#define DMODEL   64
#define DSTATE   16
#define DINNER   128
#define MLPH     64
#define BATCH    512
#define XCP      132
#define NG       4      // channel-groups (time segments) per block
#define GSEG     84     // timesteps per group
#define CHK      12     // timesteps per chunk
#define NCH      7      // chunks per group (7*12 = 84)
#define HSTR     20     // hpart record stride (breaks stride-16 bank aliasing)

typedef float v2f __attribute__((ext_vector_type(2)));

__device__ __forceinline__ float fast_rcp(float x) { return __builtin_amdgcn_rcpf(x); }
__device__ __forceinline__ float silu_f(float x) {
    return x * fast_rcp(1.f + __expf(-x));
}

// R11 = R8 restored verbatim (best: 91.6us on-device; wave-specialized
// [pair-A2(c) || conv(c+1)] | bar | scan | bar; launch_bounds(512,2) gives
// natural 64-VGPR codegen -> 2 blocks/CU). R9 (pipeline, 68 VGPR) and R10
// ((512,4) cap + in-loop side tasks -> scratch spill, 55MB writes) both
// regressed; any change adding live state to the main loop is disqualified.
// Only tail tweak here: E3 uses all 512 lanes (16 mults + 3-shfl), E4 uses
// 384 lanes (24 mults + 2-shfl) -- tail-only, register-local.
__global__ __launch_bounds__(512, 2) void mamba_one(
    const float* __restrict__ x_raw,   const float* __restrict__ x_features,
    const float* __restrict__ embed_W, const float* __restrict__ embed_b,
    const float* __restrict__ in_W,
    const float* __restrict__ conv_W,  const float* __restrict__ conv_b,
    const float* __restrict__ xproj_W, const float* __restrict__ dt_W,
    const float* __restrict__ dt_b,    const float* __restrict__ A_log,
    const float* __restrict__ Dvec,    const float* __restrict__ out_W,
    const float* __restrict__ mlp_W1,  const float* __restrict__ mlp_b1,
    const float* __restrict__ mlp_W2,  const float* __restrict__ mlp_b2,
    const float* __restrict__ head_W,  const float* __restrict__ head_b,
    float* __restrict__ out)
{
    __shared__ __align__(16) float xrl[344];            // xrl[i]=x_raw[i-3], pad i<3
    __shared__ __align__(16) float xprojT[20*XCP];      // 10.6 KB
    __shared__ __align__(16) float xcbuf[2][NG][CHK*XCP]; // 50.7 KB double-buffered
    __shared__ __align__(16) float Bsh[NG][CHK][DSTATE];
    __shared__ __align__(16) float dtraw[NG][CHK][4];
    __shared__ float xcl[DINNER], zsil[DINNER], Cl[DSTATE], yv[DINNER];
    __shared__ float hfin[96], mlph[MLPH];

    const int tid = threadIdx.x;
    const int b   = blockIdx.x;
    const int g   = tid >> 7;            // group 0..3 (2 waves, wave-uniform)
    const int ch  = tid & 127;

    // ---- staging ----
    for (int i = tid; i < 339; i += 512)
        xrl[i] = (i >= 3) ? x_raw[b*LOOKBACK + i - 3] : 0.f;
    for (int idx = tid; idx < 20*DINNER; idx += 512) {
        int jj = idx >> 7, d = idx & 127;
        xprojT[jj*XCP + d] = xproj_W[d*36 + jj];
    }

    // ---- per-thread channel params (embed_* uniform -> scalar loads) ----
    float w1 = 0.f, w0 = 0.f;
    for (int dm = 0; dm < DMODEL; ++dm) {
        float w = in_W[dm*(2*DINNER) + ch];
        w1 = fmaf(embed_W[dm], w, w1);
        w0 = fmaf(embed_b[dm], w, w0);
    }
    const float4 cw = *(const float4*)&conv_W[ch*4];
    const float  cb = conv_b[ch];
    const float dtw0 = dt_W[ch],       dtw1 = dt_W[128 + ch],
                dtw2 = dt_W[256 + ch], dtw3 = dt_W[384 + ch];
    const float dtb_r = dt_b[ch];
    bool structured = true;
    #pragma unroll
    for (int i = 0; i < 16; ++i) {
        float a = __expf(A_log[ch*DSTATE + i]);
        float ex = (float)(i + 1);
        structured = structured && (fabsf(a - ex) < 1e-3f * ex);
    }
    const bool sfast = __all(structured);

    // pair-A2 task decode (waves 0-3, tid<240): lane covers groups 2*sub,+1
    const int a2jp  = tid / 24;              // 0..9 for tid<240
    const int a2rem = tid - a2jp*24;
    const int a2sub = a2rem / 12;            // 0 or 1
    const int a2tt  = a2rem - a2sub*12;      // 0..11
    // dual-conv decode (waves 4-7): channel + first group of {g, g+2}
    const int cch    = (tid - 256) & 127;
    const int gfirst = (tid - 256) >> 7;     // 0 (waves 4,5) or 1 (waves 6,7)
    __syncthreads();   // xrl/xprojT ready

    // ---- conv chunk 0 into buffer 0 (all threads, own (g,ch)) ----
    {
        float* xw = &xcbuf[0][g][0];
        const float* xr = &xrl[g*GSEG];
        if (g == 0) {        // zero-padded taps at sequence start
            for (int tt = 0; tt < CHK; ++tt) {
                float acc = cb;
                if (tt >= 3) acc = fmaf(fmaf(xr[tt],   w1, w0), cw.x, acc);
                if (tt >= 2) acc = fmaf(fmaf(xr[tt+1], w1, w0), cw.y, acc);
                if (tt >= 1) acc = fmaf(fmaf(xr[tt+2], w1, w0), cw.z, acc);
                acc = fmaf(fmaf(xr[tt+3], w1, w0), cw.w, acc);
                xw[tt*XCP + ch] = silu_f(acc);
            }
        } else {
            float e0 = fmaf(xr[0], w1, w0);
            float e1 = fmaf(xr[1], w1, w0);
            float e2 = fmaf(xr[2], w1, w0);
            #pragma unroll
            for (int tt = 0; tt < CHK; ++tt) {
                float e3 = fmaf(xr[tt+3], w1, w0);
                float acc = cb + e0*cw.x + e1*cw.y + e2*cw.z + e3*cw.w;
                xw[tt*XCP + ch] = silu_f(acc);
                e0 = e1; e1 = e2; e2 = e3;
            }
        }
    }
    __syncthreads();

    // ---- main loop: [A2(c) || conv(c+1)] | bar | scan(c) | bar ----
    v2f h01={0,0},h23={0,0},h45={0,0},h67={0,0},
        h89={0,0},hAB={0,0},hCD={0,0},hEF={0,0};
    float dacc = 0.f;

    for (int c = 0; c < NCH; ++c) {
        const int buf = c & 1;

        if (tid < 240) {
            // pair-A2: 1 xproj column pair (broadcast in 24-lane span),
            // 2 xrows (one per group of its pair). Reads buf.
            const int ga = a2sub*2, gb = a2sub*2 + 1;
            const int j0 = a2jp*2;
            const float* p0  = &xprojT[j0*XCP];
            const float* p1  = &xprojT[(j0+1)*XCP];
            const float* xra = &xcbuf[buf][ga][a2tt*XCP];
            const float* xrb = &xcbuf[buf][gb][a2tt*XCP];
            v2f a0a={0,0}, a1a={0,0}, a0b={0,0}, a1b={0,0};
            #pragma unroll 4
            for (int d = 0; d < DINNER; d += 4) {
                float4 q0 = *(const float4*)(p0 + d);
                float4 q1 = *(const float4*)(p1 + d);
                float4 xa = *(const float4*)(xra + d);
                float4 xb = *(const float4*)(xrb + d);
                v2f q0l={q0.x,q0.y}, q0h={q0.z,q0.w};
                v2f q1l={q1.x,q1.y}, q1h={q1.z,q1.w};
                v2f xal={xa.x,xa.y}, xah={xa.z,xa.w};
                v2f xbl={xb.x,xb.y}, xbh={xb.z,xb.w};
                a0a = __builtin_elementwise_fma(xal, q0l, a0a);
                a0a = __builtin_elementwise_fma(xah, q0h, a0a);
                a1a = __builtin_elementwise_fma(xal, q1l, a1a);
                a1a = __builtin_elementwise_fma(xah, q1h, a1a);
                a0b = __builtin_elementwise_fma(xbl, q0l, a0b);
                a0b = __builtin_elementwise_fma(xbh, q0h, a0b);
                a1b = __builtin_elementwise_fma(xbl, q1l, a1b);
                a1b = __builtin_elementwise_fma(xbh, q1h, a1b);
            }
            float r0a=a0a.x+a0a.y, r1a=a1a.x+a1a.y;
            float r0b=a0b.x+a0b.y, r1b=a1b.x+a1b.y;
            if (j0 < 4) {
                *(float2*)&dtraw[ga][a2tt][j0] = make_float2(r0a, r1a);
                *(float2*)&dtraw[gb][a2tt][j0] = make_float2(r0b, r1b);
            } else {
                *(float2*)&Bsh[ga][a2tt][j0-4] = make_float2(r0a, r1a);
                *(float2*)&Bsh[gb][a2tt][j0-4] = make_float2(r0b, r1b);
            }
        } else if (tid >= 256 && c + 1 < NCH) {
            // dual-conv: chunk c+1 for groups gfirst and gfirst+2 into buf^1.
            // t0 = gg*84 + (c+1)*12 >= 12, so no zero-pad branch needed.
            #pragma unroll
            for (int q = 0; q < 2; ++q) {
                const int gg = gfirst + q*2;
                float* xw = &xcbuf[buf^1][gg][0];
                const float* xr = &xrl[gg*GSEG + (c+1)*CHK];
                float e0 = fmaf(xr[0], w1, w0);
                float e1 = fmaf(xr[1], w1, w0);
                float e2 = fmaf(xr[2], w1, w0);
                float v = 0.f;
                #pragma unroll
                for (int tt = 0; tt < CHK; ++tt) {
                    float e3 = fmaf(xr[tt+3], w1, w0);
                    float acc = cb + e0*cw.x + e1*cw.y + e2*cw.z + e3*cw.w;
                    v = silu_f(acc);
                    xw[tt*XCP + cch] = v;
                    e0 = e1; e1 = e2; e2 = e3;
                }
                if (gg == NG-1 && c + 1 == NCH-1) xcl[cch] = v;   // t = 335
            }
        }
        __syncthreads();   // dtraw/Bsh(c) + conv(c+1) ready

        // ---- phase 2: pure scan chunk c (reads buf) ----
        const float* xs = &xcbuf[buf][g][0];
        if (__builtin_expect(sfast, 1)) {
            #pragma unroll
            for (int tt = 0; tt < CHK; ++tt) {
                float4 dr = *(const float4*)&dtraw[g][tt][0];    // broadcast
                float dv = fmaf(dr.x, dtw0, fmaf(dr.y, dtw1,
                           fmaf(dr.z, dtw2, fmaf(dr.w, dtw3, dtb_r))));
                float e  = __expf(dv);
                float p  = 1.f + e;
                float r  = fast_rcp(p);                  // exp(-delta)
                float dl = (dv > 80.f) ? dv : __logf(p); // delta
                dacc += dl;
                float ux = dl * xs[tt*XCP + ch];
                float4 B0 = *(const float4*)&Bsh[g][tt][0];
                float4 B1 = *(const float4*)&Bsh[g][tt][4];
                float4 B2 = *(const float4*)&Bsh[g][tt][8];
                float4 B3 = *(const float4*)&Bsh[g][tt][12];
                // shallow power tree: depth 3 instead of 8
                float r2 = r*r, r4 = r2*r2, r8 = r4*r4;
                v2f r2v = {r2, r2}, r4v = {r4, r4}, r8v = {r8, r8};
                v2f p01 = {r, r2};
                v2f p23 = p01*r2v;
                v2f p45 = p01*r4v, p67 = p23*r4v;
                v2f p89 = p01*r8v, pAB = p23*r8v, pCD = p45*r8v, pEF = p67*r8v;
                v2f uxv = {ux, ux};
                h01 = __builtin_elementwise_fma(p01, h01, uxv*(v2f){B0.x,B0.y});
                h23 = __builtin_elementwise_fma(p23, h23, uxv*(v2f){B0.z,B0.w});
                h45 = __builtin_elementwise_fma(p45, h45, uxv*(v2f){B1.x,B1.y});
                h67 = __builtin_elementwise_fma(p67, h67, uxv*(v2f){B1.z,B1.w});
                h89 = __builtin_elementwise_fma(p89, h89, uxv*(v2f){B2.x,B2.y});
                hAB = __builtin_elementwise_fma(pAB, hAB, uxv*(v2f){B2.z,B2.w});
                hCD = __builtin_elementwise_fma(pCD, hCD, uxv*(v2f){B3.x,B3.y});
                hEF = __builtin_elementwise_fma(pEF, hEF, uxv*(v2f){B3.z,B3.w});
            }
        } else {
            const float* Arow = A_log + ch*DSTATE;
            for (int tt = 0; tt < CHK; ++tt) {
                float4 dr = *(const float4*)&dtraw[g][tt][0];
                float dv = fmaf(dr.x, dtw0, fmaf(dr.y, dtw1,
                           fmaf(dr.z, dtw2, fmaf(dr.w, dtw3, dtb_r))));
                float e  = __expf(dv);
                float dl = (dv > 15.f) ? dv : __logf(1.f + e);
                dacc += dl;
                float ux = dl * xs[tt*XCP + ch];
                const float* Brow = &Bsh[g][tt][0];
                float hv[16] = {h01.x,h01.y,h23.x,h23.y,h45.x,h45.y,h67.x,h67.y,
                                h89.x,h89.y,hAB.x,hAB.y,hCD.x,hCD.y,hEF.x,hEF.y};
                for (int i = 0; i < 16; ++i)
                    hv[i] = fmaf(__expf(-__expf(Arow[i])*dl), hv[i], ux*Brow[i]);
                h01=(v2f){hv[0],hv[1]};   h23=(v2f){hv[2],hv[3]};
                h45=(v2f){hv[4],hv[5]};   h67=(v2f){hv[6],hv[7]};
                h89=(v2f){hv[8],hv[9]};   hAB=(v2f){hv[10],hv[11]};
                hCD=(v2f){hv[12],hv[13]}; hEF=(v2f){hv[14],hv[15]};
            }
        }
        __syncthreads();   // scan reads done before next A2/conv overwrite
    }

    // ---- write partials to LDS (overlay dead xcbuf / Bsh regions) ----
    float* hpart = &xcbuf[0][0][0];      // needs 512*HSTR = 10240 <= 12672
    float* dsum  = &Bsh[0][0][0];        // needs 512 <= 768
    {
        float4* hp = (float4*)&hpart[(g*128 + ch)*HSTR];
        hp[0] = make_float4(h01.x,h01.y,h23.x,h23.y);
        hp[1] = make_float4(h45.x,h45.y,h67.x,h67.y);
        hp[2] = make_float4(h89.x,h89.y,hAB.x,hAB.y);
        hp[3] = make_float4(hCD.x,hCD.y,hEF.x,hEF.y);
        dsum[g*128 + ch] = dacc;
    }
    __syncthreads();

    // ---- E1 (parallel): combine | z-gate | C | mlp1 ----
    float H[16];
    if (tid < 128) {
        {
            const float4* hp = (const float4*)&hpart[tid*HSTR];
            float4 a = hp[0], bq = hp[1], cq = hp[2], dq = hp[3];
            H[0]=a.x;  H[1]=a.y;  H[2]=a.z;  H[3]=a.w;
            H[4]=bq.x; H[5]=bq.y; H[6]=bq.z; H[7]=bq.w;
            H[8]=cq.x; H[9]=cq.y; H[10]=cq.z;H[11]=cq.w;
            H[12]=dq.x;H[13]=dq.y;H[14]=dq.z;H[15]=dq.w;
        }
        for (int gg = 1; gg < NG; ++gg) {
            float D = dsum[gg*128 + tid];
            const float4* hp = (const float4*)&hpart[(gg*128 + tid)*HSTR];
            float4 a = hp[0], bq = hp[1], cq = hp[2], dq = hp[3];
            float hg[16] = {a.x,a.y,a.z,a.w,bq.x,bq.y,bq.z,bq.w,
                            cq.x,cq.y,cq.z,cq.w,dq.x,dq.y,dq.z,dq.w};
            if (structured) {
                float r = __expf(-D);
                float pw = 1.f;
                #pragma unroll
                for (int i = 0; i < 16; ++i) {
                    pw *= r;                      // r^(i+1)
                    H[i] = fmaf(pw, H[i], hg[i]);
                }
            } else {
                #pragma unroll
                for (int i = 0; i < 16; ++i)
                    H[i] = fmaf(__expf(-__expf(A_log[tid*DSTATE+i])*D), H[i], hg[i]);
            }
        }
    } else if (tid < 256) {
        const int c2 = tid - 128;                 // z-gate channel
        float a1 = 0.f, a0 = 0.f;
        for (int dm = 0; dm < DMODEL; ++dm) {
            float w = in_W[dm*(2*DINNER) + DINNER + c2];
            a1 = fmaf(embed_W[dm], w, a1);
            a0 = fmaf(embed_b[dm], w, a0);
        }
        float zv = fmaf(xrl[338], a1, a0);        // x_raw[335]
        zsil[c2] = silu_f(zv);
    } else if (tid < 320) {
        const int lane = tid - 256;               // C at t=335 (one wave)
        const int n = lane & 15, q = lane >> 4;
        float acc = 0.f;
        for (int d = q*32; d < q*32 + 32; ++d)
            acc = fmaf(xcl[d], xproj_W[d*36 + 20 + n], acc);
        acc += __shfl_xor(acc, 16);
        acc += __shfl_xor(acc, 32);
        if (lane < 16) Cl[n] = acc;
    } else if (tid >= 384) {
        const int lane = tid - 384;               // mlp1 (2 waves)
        const int j = lane >> 1, k = lane & 1;
        const float* xf = x_features + b*NFEAT;
        float acc = 0.f;
        const int f0 = k*82, f1 = (k ? NFEAT : 82);
        for (int f = f0; f < f1; ++f)
            acc = fmaf(xf[f], mlp_W1[f*MLPH + j], acc);
        acc += __shfl_xor(acc, 1);
        if (k == 0) mlph[j] = fmaxf(acc + mlp_b1[j], 0.f);
    }
    __syncthreads();

    // ---- E2: y (tid<128) | mlp2 (tid 128..191) ----
    if (tid < 128) {
        float acc = 0.f;
        #pragma unroll
        for (int i = 0; i < 16; ++i) acc = fmaf(H[i], Cl[i], acc);
        float y = acc + xcl[tid]*Dvec[tid];
        yv[tid] = y * zsil[tid];
    } else if (tid < 192) {
        const int lane = tid - 128;
        const int j = lane >> 1, k = lane & 1;
        float acc = 0.f;
        for (int kk = k*32; kk < k*32 + 32; ++kk)
            acc = fmaf(mlph[kk], mlp_W2[kk*32 + j], acc);
        acc += __shfl_xor(acc, 1);
        if (k == 0) hfin[64 + j] = acc + mlp_b2[j];
    }
    __syncthreads();

    // ---- E3: out projection, all 512 lanes (16 mults + 3-level shfl) ----
    {
        const int o = tid >> 3, k = tid & 7;      // 64 outs x 8 k-lanes
        float acc = 0.f;
        for (int d = k*16; d < k*16 + 16; ++d)
            acc = fmaf(yv[d], out_W[d*DMODEL + o], acc);
        acc += __shfl_xor(acc, 1);
        acc += __shfl_xor(acc, 2);
        acc += __shfl_xor(acc, 4);
        if (k == 0) hfin[o] = acc;
    }
    __syncthreads();

    // ---- E4: head, 384 lanes (24 mults + 2-level shfl) ----
    if (tid < 384) {
        const int o = tid >> 2, k = tid & 3;      // 96 outs x 4 k-lanes
        float acc = 0.f;
        for (int i = k*24; i < k*24 + 24; ++i)
            acc = fmaf(hfin[i], head_W[i*HORIZON + o], acc);
        acc += __shfl_xor(acc, 1);
        acc += __shfl_xor(acc, 2);
        if (k == 0) out[b*HORIZON + o] = acc + head_b[o];
    }
}

extern "C" void kernel_launch(void* const* d_in, const int* in_sizes, int n_in,
                              void* d_out, int out_size, void* d_ws, size_t ws_size,
                              hipStream_t stream) {
    (void)in_sizes; (void)n_in; (void)out_size; (void)d_ws; (void)ws_size;
    mamba_one<<<BATCH, 512, 0, stream>>>(
        (const float*)d_in[0],  (const float*)d_in[1],  (const float*)d_in[2],
        (const float*)d_in[3],  (const float*)d_in[4],  (const float*)d_in[5],
        (const float*)d_in[6],  (const float*)d_in[7],  (const float*)d_in[8],
        (const float*)d_in[9],  (const float*)d_in[10], (const float*)d_in[11],
        (const float*)d_in[12], (const float*)d_in[13], (const float*)d_in[14],
        (const float*)d_in[15], (const float*)d_in[16], (const float*)d_in[17],
        (const float*)d_in[18], (float*)d_out);
}